// Round 5
// baseline (8736.045 us; speedup 1.0000x reference)
//
#include <hip/hip_runtime.h>
#include <math.h>

// Problem dims (fixed by setup_inputs)
#define B_ROWS 65536
#define DDIM   512
#define NG     4
#define NK     1024
#define NH     128
#define NA     7

// Tiling
#define BM       32            // rows per block
#define NTHREADS 512           // 8 waves
#define TR       16            // rows per lane (2 rowgroups of 16)
#define CWCHUNK  256           // codeword tile width
#define NCWC     (NK / CWCHUNK)      // 4
#define KCHUNK   32            // k tile (double-buffered)
#define NKC      (DDIM / KCHUNK)     // 16
#define KC_SPLIT 12            // kc<12 -> accA (k<384, OpenBLAS GEMM_Q block)

// LDS layout
#define BT_ELEMS  (KCHUNK * CWCHUNK)                 // 8192 floats per buffer
#define OFF_BTILE (BM * DDIM * 4)                    // 65536
#define OFF_H1    (OFF_BTILE + 2 * BT_ELEMS * 4)     // 131072
#define OFF_REDS  (OFF_H1 + BM * NH * 4)             // 147456
#define OFF_REDI  (OFF_REDS + 4 * BM * 4)            // 147968
#define OFF_IDX   (OFF_REDI + 4 * BM * 4)            // 148480
#define LDS_BYTES (OFF_IDX + NG * BM * 4)            // 148992

// ---------------------------------------------------------------------------
// 0.5 * ||c||^2 emulating numpy fp32 np.sum(C*C, axis=-1):
// pairwise_sum, AVX512 SIMD variant (vstep=16, PW_BLOCKSIZE=128).
// fp contract OFF: each square rounds before add (C*C is a materialized array).
// ---------------------------------------------------------------------------
__global__ void rvq_norms_np(const float* __restrict__ cb,
                             float* __restrict__ halfnorm) {
#pragma clang fp contract(off)
    int k = blockIdx.x * blockDim.x + threadIdx.x;
    if (k >= NG * NK) return;
    const float* c = cb + (size_t)k * DDIM;
    float blk[4];
#pragma unroll
    for (int b = 0; b < 4; ++b) {
        const float* p = c + b * 128;
        float s[16];
#pragma unroll
        for (int l = 0; l < 16; ++l) {
            float x0 = p[l],      x1 = p[l + 16], x2 = p[l + 32], x3 = p[l + 48];
            float x4 = p[l + 64], x5 = p[l + 80], x6 = p[l + 96], x7 = p[l + 112];
            float pa = x0 * x0 + x4 * x4;
            float pb = x1 * x1 + x5 * x5;
            float pc = x2 * x2 + x6 * x6;
            float pd = x3 * x3 + x7 * x7;
            s[l] = (pa + pb) + (pc + pd);
        }
        float h[8];
#pragma unroll
        for (int l = 0; l < 8; ++l) h[l] = s[l] + s[l + 8];
        float q[4];
#pragma unroll
        for (int l = 0; l < 4; ++l) q[l] = h[l] + h[l + 4];
        float r0 = q[0] + q[2];
        float r1 = q[1] + q[3];
        blk[b] = r0 + r1;
    }
    float total = (blk[0] + blk[1]) + (blk[2] + blk[3]);
    halfnorm[k] = 0.5f * total;
}

// One k-subchunk of the bit-exact sequential fp32 FMA chain (ascending d).
// B: per-lane b32 stride-4B (2-way bank = free). A: wave-uniform b128 broadcast.
#define COMPUTE_CHUNK(BT, ACC)                                                \
    _Pragma("unroll")                                                         \
    for (int d4 = 0; d4 < KCHUNK; d4 += 4) {                                  \
        float bq0 = BT[(d4 + 0) * CWCHUNK + bcol];                            \
        float bq1 = BT[(d4 + 1) * CWCHUNK + bcol];                            \
        float bq2 = BT[(d4 + 2) * CWCHUNK + bcol];                            \
        float bq3 = BT[(d4 + 3) * CWCHUNK + bcol];                            \
        _Pragma("unroll")                                                     \
        for (int r = 0; r < TR; ++r) {                                        \
            float4 av = *(const float4*)&resid[(r0 + r) * DDIM + kb + d4];    \
            ACC[r] = fmaf(av.x, bq0, ACC[r]);                                 \
            ACC[r] = fmaf(av.y, bq1, ACC[r]);                                 \
            ACC[r] = fmaf(av.z, bq2, ACC[r]);                                 \
            ACC[r] = fmaf(av.w, bq3, ACC[r]);                                 \
        }                                                                     \
    }

// ---------------------------------------------------------------------------
// Fused: residual VQ (4 stages, np-fp32-emulated scoring, LDS-tiled GEMM with
// double-buffered B tile) + reference-order quantized sum + straight-through
// + MLP (512->128->128->7).
// ---------------------------------------------------------------------------
__global__ __launch_bounds__(NTHREADS, 2) void rvq_mlp_fused(
    const float* __restrict__ z, const float* __restrict__ cb,
    const float* __restrict__ halfnorm,
    const float* __restrict__ w1, const float* __restrict__ b1,
    const float* __restrict__ w2, const float* __restrict__ b2,
    const float* __restrict__ w3, const float* __restrict__ b3,
    float* __restrict__ out) {
    extern __shared__ char smem[];
    float* resid = (float*)smem;                   // [BM][DDIM]
    float* Bt    = (float*)(smem + OFF_BTILE);     // [2][KCHUNK][CWCHUNK]
    float* h1    = (float*)(smem + OFF_H1);        // [BM][NH]
    float* redS  = (float*)(smem + OFF_REDS);      // [4][BM]
    int*   redI  = (int*)(smem + OFF_REDI);        // [4][BM]
    int*   idx_s = (int*)(smem + OFF_IDX);         // [NG][BM]

    const int tid = threadIdx.x;
    const size_t row0 = (size_t)blockIdx.x * BM;

    // ---- 1) load z tile into LDS ----
    {
        const float4* src = (const float4*)(z + row0 * DDIM);
        float4* dst = (float4*)resid;
#pragma unroll
        for (int i = 0; i < (BM * DDIM / 4) / NTHREADS; ++i)
            dst[tid + i * NTHREADS] = src[tid + i * NTHREADS];
    }
    __syncthreads();

    const int cg   = tid & 63;       // lane
    const int wv   = tid >> 6;       // wave 0..7
    const int rgrp = wv & 1;         // row-group (16 rows each)
    const int qtr  = wv >> 1;        // codeword quarter (64 cw each)
    const int r0   = rgrp * TR;
    const int bcol = qtr * 64 + cg;  // lane's codeword within chunk

    // staging identities (2 threads per codeword row, 16 k each)
    const int scw   = tid >> 1;           // 0..255
    const int skoff = (tid & 1) * 16;     // 0 or 16

    // ---- 2) residual VQ stages ----
    for (int g = 0; g < NG; ++g) {
        const float* C  = cb + (size_t)g * NK * DDIM;
        const float* hn = halfnorm + g * NK;

        float sb[TR]; int ib[TR];
#pragma unroll
        for (int r = 0; r < TR; ++r) { sb[r] = -3.4e38f; ib[r] = 0; }

        for (int cwc = 0; cwc < NCWC; ++cwc) {
            const int cbase = cwc * CWCHUNK;
            float accA[TR], accB[TR];
#pragma unroll
            for (int r = 0; r < TR; ++r) { accA[r] = 0.f; accB[r] = 0.f; }

            const float* srow = C + (size_t)(cbase + scw) * DDIM + skoff;

            // prologue: stage k-chunk 0 -> buf0 (writes 2-way bank = free)
            {
                float4 stv[4];
#pragma unroll
                for (int i = 0; i < 4; ++i)
                    stv[i] = *(const float4*)(srow + 4 * i);
#pragma unroll
                for (int i = 0; i < 4; ++i) {
                    const float* pv = (const float*)&stv[i];
#pragma unroll
                    for (int c = 0; c < 4; ++c)
                        Bt[(skoff + 4 * i + c) * CWCHUNK + scw] = pv[c];
                }
            }

            for (int kc = 0; kc < NKC; ++kc) {
                const int kb = kc * KCHUNK;
                __syncthreads();   // buf[kc&1] visible; prev readers of buf[(kc+1)&1] done
                float4 stv[4];
                if (kc + 1 < NKC) {   // T14: issue next-chunk loads early
#pragma unroll
                    for (int i = 0; i < 4; ++i)
                        stv[i] = *(const float4*)(srow + (kb + KCHUNK) + 4 * i);
                }
                const float* bt = Bt + (kc & 1) * BT_ELEMS;
                if (kc < KC_SPLIT) { COMPUTE_CHUNK(bt, accA) }
                else               { COMPUTE_CHUNK(bt, accB) }
                if (kc + 1 < NKC) {   // write-late into the idle buffer
                    float* btN = Bt + ((kc + 1) & 1) * BT_ELEMS;
#pragma unroll
                    for (int i = 0; i < 4; ++i) {
                        const float* pv = (const float*)&stv[i];
#pragma unroll
                        for (int c = 0; c < 4; ++c)
                            btN[(skoff + 4 * i + c) * CWCHUNK + scw] = pv[c];
                    }
                }
            }

            // score = fl(S1+S2) - hn ; running argmax (cbase ascending -> strict >
            // keeps first occurrence)
            {
                const int cod = cbase + bcol;
                const float hnv = hn[cod];
#pragma unroll
                for (int r = 0; r < TR; ++r) {
                    float s = (accA[r] + accB[r]) - hnv;
                    if (s > sb[r]) { sb[r] = s; ib[r] = cod; }
                }
            }
        }

        // ---- butterfly argmax within wave (ties -> lower index) ----
#pragma unroll
        for (int m = 32; m >= 1; m >>= 1) {
#pragma unroll
            for (int r = 0; r < TR; ++r) {
                float os = __shfl_xor(sb[r], m, 64);
                int   oi = __shfl_xor(ib[r], m, 64);
                if (os > sb[r] || (os == sb[r] && oi < ib[r])) {
                    sb[r] = os; ib[r] = oi;
                }
            }
        }
        if (cg == 0) {
#pragma unroll
            for (int r = 0; r < TR; ++r) {
                redS[qtr * BM + r0 + r] = sb[r];
                redI[qtr * BM + r0 + r] = ib[r];
            }
        }
        __syncthreads();
        // combine the four cw-quarters per row (global first-occurrence ties)
        if (tid < BM) {
            float bs = redS[tid]; int bi = redI[tid];
#pragma unroll
            for (int q = 1; q < 4; ++q) {
                float s = redS[q * BM + tid];
                int   i = redI[q * BM + tid];
                if (s > bs || (s == bs && i < bi)) { bs = s; bi = i; }
            }
            idx_s[g * BM + tid] = bi;
        }
        __syncthreads();

        // ---- residual -= chosen codeword (exact fp32); skip after last ----
        if (g < NG - 1) {
            const int row = tid >> 4;
            const int sub = tid & 15;
            const float4* crow =
                (const float4*)(C + (size_t)idx_s[g * BM + row] * DDIM);
            float4* rrow = (float4*)&resid[row * DDIM];
#pragma unroll
            for (int k = 0; k < 8; ++k) {
                int p = sub + k * 16;
                float4 rv = rrow[p], cv = crow[p];
                rv.x -= cv.x; rv.y -= cv.y; rv.z -= cv.z; rv.w -= cv.w;
                rrow[p] = rv;
            }
            __syncthreads();
        }
    }

    // ---- 3) st = z + (zq - z), zq in reference order (((0+q0)+q1)+q2)+q3 ----
    {
        const int row = tid >> 4;
        const int sub = tid & 15;
        const float4* zrow = (const float4*)(z + (row0 + row) * DDIM);
        float4* rrow = (float4*)&resid[row * DDIM];
        const float4* c0 = (const float4*)(cb + ((size_t)0 * NK + idx_s[0 * BM + row]) * DDIM);
        const float4* c1 = (const float4*)(cb + ((size_t)1 * NK + idx_s[1 * BM + row]) * DDIM);
        const float4* c2 = (const float4*)(cb + ((size_t)2 * NK + idx_s[2 * BM + row]) * DDIM);
        const float4* c3 = (const float4*)(cb + ((size_t)3 * NK + idx_s[3 * BM + row]) * DDIM);
#pragma unroll
        for (int k = 0; k < 8; ++k) {
            int p = sub + k * 16;
            float4 q0 = c0[p], q1 = c1[p], q2 = c2[p], q3 = c3[p];
            float4 q;
            q.x = ((q0.x + q1.x) + q2.x) + q3.x;
            q.y = ((q0.y + q1.y) + q2.y) + q3.y;
            q.z = ((q0.z + q1.z) + q2.z) + q3.z;
            q.w = ((q0.w + q1.w) + q2.w) + q3.w;
            float4 zv = zrow[p];
            float4 st;
            st.x = zv.x + (q.x - zv.x);
            st.y = zv.y + (q.y - zv.y);
            st.z = zv.z + (q.z - zv.z);
            st.w = zv.w + (q.w - zv.w);
            rrow[p] = st;
        }
    }
    __syncthreads();

    const int colg = tid & 31;
    const int rowg = tid >> 5;
    const int c0_  = colg * 4;
    const int hr0  = rowg * 2;

    // ---- 4) h1 = relu(st @ w1 + b1) ----
    {
        float acc[2][4] = {{0.f, 0.f, 0.f, 0.f}, {0.f, 0.f, 0.f, 0.f}};
        for (int d = 0; d < DDIM; d += 4) {
            float4 a0 = *(const float4*)&resid[hr0 * DDIM + d];
            float4 a1 = *(const float4*)&resid[(hr0 + 1) * DDIM + d];
            float a0f[4] = {a0.x, a0.y, a0.z, a0.w};
            float a1f[4] = {a1.x, a1.y, a1.z, a1.w};
#pragma unroll
            for (int dd = 0; dd < 4; ++dd) {
                float4 wv2 = *(const float4*)&w1[(size_t)(d + dd) * NH + c0_];
                acc[0][0] = fmaf(a0f[dd], wv2.x, acc[0][0]);
                acc[0][1] = fmaf(a0f[dd], wv2.y, acc[0][1]);
                acc[0][2] = fmaf(a0f[dd], wv2.z, acc[0][2]);
                acc[0][3] = fmaf(a0f[dd], wv2.w, acc[0][3]);
                acc[1][0] = fmaf(a1f[dd], wv2.x, acc[1][0]);
                acc[1][1] = fmaf(a1f[dd], wv2.y, acc[1][1]);
                acc[1][2] = fmaf(a1f[dd], wv2.z, acc[1][2]);
                acc[1][3] = fmaf(a1f[dd], wv2.w, acc[1][3]);
            }
        }
        float4 bv = *(const float4*)&b1[c0_];
        float bf[4] = {bv.x, bv.y, bv.z, bv.w};
#pragma unroll
        for (int r = 0; r < 2; ++r) {
            float4 o;
            o.x = fmaxf(acc[r][0] + bf[0], 0.f);
            o.y = fmaxf(acc[r][1] + bf[1], 0.f);
            o.z = fmaxf(acc[r][2] + bf[2], 0.f);
            o.w = fmaxf(acc[r][3] + bf[3], 0.f);
            *(float4*)&h1[(hr0 + r) * NH + c0_] = o;
        }
    }
    __syncthreads();

    // ---- 5) h2 = relu(h1 @ w2 + b2), stored into resid region ----
    float* h2 = resid;
    {
        float acc[2][4] = {{0.f, 0.f, 0.f, 0.f}, {0.f, 0.f, 0.f, 0.f}};
        for (int d = 0; d < NH; d += 4) {
            float4 a0 = *(const float4*)&h1[hr0 * NH + d];
            float4 a1 = *(const float4*)&h1[(hr0 + 1) * NH + d];
            float a0f[4] = {a0.x, a0.y, a0.z, a0.w};
            float a1f[4] = {a1.x, a1.y, a1.z, a1.w};
#pragma unroll
            for (int dd = 0; dd < 4; ++dd) {
                float4 wv2 = *(const float4*)&w2[(size_t)(d + dd) * NH + c0_];
                acc[0][0] = fmaf(a0f[dd], wv2.x, acc[0][0]);
                acc[0][1] = fmaf(a0f[dd], wv2.y, acc[0][1]);
                acc[0][2] = fmaf(a0f[dd], wv2.z, acc[0][2]);
                acc[0][3] = fmaf(a0f[dd], wv2.w, acc[0][3]);
                acc[1][0] = fmaf(a1f[dd], wv2.x, acc[1][0]);
                acc[1][1] = fmaf(a1f[dd], wv2.y, acc[1][1]);
                acc[1][2] = fmaf(a1f[dd], wv2.z, acc[1][2]);
                acc[1][3] = fmaf(a1f[dd], wv2.w, acc[1][3]);
            }
        }
        float4 bv = *(const float4*)&b2[c0_];
        float bf[4] = {bv.x, bv.y, bv.z, bv.w};
        __syncthreads();
#pragma unroll
        for (int r = 0; r < 2; ++r) {
            float4 o;
            o.x = fmaxf(acc[r][0] + bf[0], 0.f);
            o.y = fmaxf(acc[r][1] + bf[1], 0.f);
            o.z = fmaxf(acc[r][2] + bf[2], 0.f);
            o.w = fmaxf(acc[r][3] + bf[3], 0.f);
            *(float4*)&h2[(hr0 + r) * NH + c0_] = o;
        }
    }
    __syncthreads();

    // ---- 6) out = h2 @ w3 + b3 ----
    if (tid < BM * NA) {
        const int r = tid / NA;
        const int a = tid - r * NA;
        const float* h2r = &h2[r * NH];
        float s = b3[a];
        for (int h = 0; h < NH; ++h)
            s = fmaf(h2r[h], w3[(size_t)h * NA + a], s);
        out[(row0 + r) * NA + a] = s;
    }
}

extern "C" void kernel_launch(void* const* d_in, const int* in_sizes, int n_in,
                              void* d_out, int out_size, void* d_ws, size_t ws_size,
                              hipStream_t stream) {
    const float* z  = (const float*)d_in[0];
    const float* cb = (const float*)d_in[1];
    const float* w1 = (const float*)d_in[2];
    const float* b1 = (const float*)d_in[3];
    const float* w2 = (const float*)d_in[4];
    const float* b2 = (const float*)d_in[5];
    const float* w3 = (const float*)d_in[6];
    const float* b3 = (const float*)d_in[7];
    float* out = (float*)d_out;
    float* halfnorm = (float*)d_ws;   // NG*NK floats = 16 KB

    (void)hipFuncSetAttribute((const void*)rvq_mlp_fused,
                              hipFuncAttributeMaxDynamicSharedMemorySize,
                              LDS_BYTES);

    rvq_norms_np<<<dim3((NG * NK + 255) / 256), dim3(256), 0, stream>>>(cb, halfnorm);
    rvq_mlp_fused<<<dim3(B_ROWS / BM), dim3(NTHREADS), LDS_BYTES, stream>>>(
        z, cb, halfnorm, w1, b1, w2, b2, w3, b3, out);
}

// Round 6
// 4980.539 us; speedup vs baseline: 1.7540x; 1.7540x over previous
//
#include <hip/hip_runtime.h>
#include <math.h>

// Problem dims (fixed by setup_inputs)
#define B_ROWS 65536
#define DDIM   512
#define NG     4
#define NK     1024
#define NH     128
#define NA     7

// Tiling: 8 waves = 4 row-groups (TR=8 rows) x 2 cw-groups (TC=4 cols/lane)
// LDS-read dwords per FMA = 1/TC + 1/TR = 0.375 (r4: 0.625, r5: 1.06)
#define BM       32            // rows per block
#define NTHREADS 512           // 8 waves
#define TR       8             // rows per lane
#define TC       4             // codewords per lane (stride 64)
#define CWCHUNK  512           // codeword tile width
#define NCWC     (NK / CWCHUNK)      // 2
#define KCHUNK   16            // k tile (double-buffered)
#define NKC      (DDIM / KCHUNK)     // 32
#define KC_SPLIT 24            // kc<24 -> accA (k<384, OpenBLAS GEMM_Q block)

// LDS layout
#define BT_ELEMS  (KCHUNK * CWCHUNK)                 // 8192 floats per buffer
#define OFF_BTILE (BM * DDIM * 4)                    // 65536
#define OFF_H1    (OFF_BTILE + 2 * BT_ELEMS * 4)     // 131072
#define OFF_REDS  (OFF_H1 + BM * NH * 4)             // 147456
#define OFF_REDI  (OFF_REDS + 2 * BM * 4)            // 147712
#define OFF_IDX   (OFF_REDI + 2 * BM * 4)            // 147968
#define LDS_BYTES (OFF_IDX + NG * BM * 4)            // 148480

// ---------------------------------------------------------------------------
// 0.5 * ||c||^2 emulating numpy fp32 np.sum(C*C, axis=-1):
// pairwise_sum, AVX512 SIMD variant (vstep=16, PW_BLOCKSIZE=128).
// fp contract OFF: each square rounds before add (C*C is a materialized array).
// ---------------------------------------------------------------------------
__global__ void rvq_norms_np(const float* __restrict__ cb,
                             float* __restrict__ halfnorm) {
#pragma clang fp contract(off)
    int k = blockIdx.x * blockDim.x + threadIdx.x;
    if (k >= NG * NK) return;
    const float* c = cb + (size_t)k * DDIM;
    float blk[4];
#pragma unroll
    for (int b = 0; b < 4; ++b) {
        const float* p = c + b * 128;
        float s[16];
#pragma unroll
        for (int l = 0; l < 16; ++l) {
            float x0 = p[l],      x1 = p[l + 16], x2 = p[l + 32], x3 = p[l + 48];
            float x4 = p[l + 64], x5 = p[l + 80], x6 = p[l + 96], x7 = p[l + 112];
            float pa = x0 * x0 + x4 * x4;
            float pb = x1 * x1 + x5 * x5;
            float pc = x2 * x2 + x6 * x6;
            float pd = x3 * x3 + x7 * x7;
            s[l] = (pa + pb) + (pc + pd);
        }
        float h[8];
#pragma unroll
        for (int l = 0; l < 8; ++l) h[l] = s[l] + s[l + 8];
        float q[4];
#pragma unroll
        for (int l = 0; l < 4; ++l) q[l] = h[l] + h[l + 4];
        float r0 = q[0] + q[2];
        float r1 = q[1] + q[3];
        blk[b] = r0 + r1;
    }
    float total = (blk[0] + blk[1]) + (blk[2] + blk[3]);
    halfnorm[k] = 0.5f * total;
}

// One k-subchunk of the bit-exact sequential fp32 FMA chain (ascending d).
// B: per-lane b32 stride-4B across lanes (2-way bank = free), TC=4 at stride 64.
// A: wave-uniform b128, amortized over TC=4 columns.
#define COMPUTE_CHUNK(BT, ACC)                                                \
    _Pragma("unroll")                                                         \
    for (int d4 = 0; d4 < KCHUNK; d4 += 4) {                                  \
        float bq[TC][4];                                                      \
        _Pragma("unroll")                                                     \
        for (int j = 0; j < TC; ++j)                                          \
            _Pragma("unroll")                                                 \
            for (int dd = 0; dd < 4; ++dd)                                    \
                bq[j][dd] = BT[(d4 + dd) * CWCHUNK + cwoff + j * 64 + cg];    \
        _Pragma("unroll")                                                     \
        for (int r = 0; r < TR; ++r) {                                        \
            float4 av = *(const float4*)&resid[(r0 + r) * DDIM + kb + d4];    \
            _Pragma("unroll")                                                 \
            for (int j = 0; j < TC; ++j) {                                    \
                ACC[r][j] = fmaf(av.x, bq[j][0], ACC[r][j]);                  \
                ACC[r][j] = fmaf(av.y, bq[j][1], ACC[r][j]);                  \
                ACC[r][j] = fmaf(av.z, bq[j][2], ACC[r][j]);                  \
                ACC[r][j] = fmaf(av.w, bq[j][3], ACC[r][j]);                  \
            }                                                                 \
        }                                                                     \
    }

// ---------------------------------------------------------------------------
// Fused: residual VQ (4 stages, np-fp32-emulated scoring, LDS-tiled GEMM with
// double-buffered B tile) + reference-order quantized sum + straight-through
// + MLP (512->128->128->7).
// ---------------------------------------------------------------------------
__global__ __launch_bounds__(NTHREADS, 2) void rvq_mlp_fused(
    const float* __restrict__ z, const float* __restrict__ cb,
    const float* __restrict__ halfnorm,
    const float* __restrict__ w1, const float* __restrict__ b1,
    const float* __restrict__ w2, const float* __restrict__ b2,
    const float* __restrict__ w3, const float* __restrict__ b3,
    float* __restrict__ out) {
    extern __shared__ char smem[];
    float* resid = (float*)smem;                   // [BM][DDIM]
    float* Bt    = (float*)(smem + OFF_BTILE);     // [2][KCHUNK][CWCHUNK]
    float* h1    = (float*)(smem + OFF_H1);        // [BM][NH]
    float* redS  = (float*)(smem + OFF_REDS);      // [2][BM]
    int*   redI  = (int*)(smem + OFF_REDI);        // [2][BM]
    int*   idx_s = (int*)(smem + OFF_IDX);         // [NG][BM]

    const int tid = threadIdx.x;
    const size_t row0 = (size_t)blockIdx.x * BM;

    // ---- 1) load z tile into LDS ----
    {
        const float4* src = (const float4*)(z + row0 * DDIM);
        float4* dst = (float4*)resid;
#pragma unroll
        for (int i = 0; i < (BM * DDIM / 4) / NTHREADS; ++i)
            dst[tid + i * NTHREADS] = src[tid + i * NTHREADS];
    }
    __syncthreads();

    const int cg    = tid & 63;       // lane
    const int wv    = tid >> 6;       // wave 0..7
    const int rgrp  = wv & 3;         // row-group (8 rows each)
    const int cwgrp = wv >> 2;        // cw-group (256 cw each)
    const int r0    = rgrp * TR;
    const int cwoff = cwgrp * 256;    // lane cols: cwoff + j*64 + cg

    // staging identity: 1 thread per codeword row, 16 k each
    const int scw = tid;              // 0..511

    // ---- 2) residual VQ stages ----
    for (int g = 0; g < NG; ++g) {
        const float* C  = cb + (size_t)g * NK * DDIM;
        const float* hn = halfnorm + g * NK;

        float sb[TR]; int ib[TR];
#pragma unroll
        for (int r = 0; r < TR; ++r) { sb[r] = -3.4e38f; ib[r] = 0; }

        for (int cwc = 0; cwc < NCWC; ++cwc) {
            const int cbase = cwc * CWCHUNK;
            float accA[TR][TC], accB[TR][TC];
#pragma unroll
            for (int r = 0; r < TR; ++r)
#pragma unroll
                for (int j = 0; j < TC; ++j) { accA[r][j] = 0.f; accB[r][j] = 0.f; }

            const float* srow = C + (size_t)(cbase + scw) * DDIM;

            // prologue: stage k-chunk 0 -> buf0
            {
                float4 stv[4];
#pragma unroll
                for (int i = 0; i < 4; ++i)
                    stv[i] = *(const float4*)(srow + 4 * i);
#pragma unroll
                for (int i = 0; i < 4; ++i) {
                    const float* pv = (const float*)&stv[i];
#pragma unroll
                    for (int c = 0; c < 4; ++c)
                        Bt[(4 * i + c) * CWCHUNK + scw] = pv[c];
                }
            }

            for (int kc = 0; kc < NKC; ++kc) {
                const int kb = kc * KCHUNK;
                __syncthreads();   // buf[kc&1] visible; readers of buf[(kc+1)&1] done
                float4 stv[4];
                if (kc + 1 < NKC) {   // T14: issue next-chunk loads early
#pragma unroll
                    for (int i = 0; i < 4; ++i)
                        stv[i] = *(const float4*)(srow + (kb + KCHUNK) + 4 * i);
                }
                const float* bt = Bt + (kc & 1) * BT_ELEMS;
                if (kc < KC_SPLIT) { COMPUTE_CHUNK(bt, accA) }
                else               { COMPUTE_CHUNK(bt, accB) }
                if (kc + 1 < NKC) {   // write-late into the idle buffer
                    float* btN = Bt + ((kc + 1) & 1) * BT_ELEMS;
#pragma unroll
                    for (int i = 0; i < 4; ++i) {
                        const float* pv = (const float*)&stv[i];
#pragma unroll
                        for (int c = 0; c < 4; ++c)
                            btN[(4 * i + c) * CWCHUNK + scw] = pv[c];
                    }
                }
            }

            // score = fl(S1+S2) - hn ; running argmax (cwc asc, j asc ->
            // candidates ascending per lane -> strict > keeps first occurrence)
#pragma unroll
            for (int j = 0; j < TC; ++j) {
                const int cod = cbase + cwoff + j * 64 + cg;
                const float hnv = hn[cod];
#pragma unroll
                for (int r = 0; r < TR; ++r) {
                    float s = (accA[r][j] + accB[r][j]) - hnv;
                    if (s > sb[r]) { sb[r] = s; ib[r] = cod; }
                }
            }
        }

        // ---- butterfly argmax within wave (ties -> lower index) ----
#pragma unroll
        for (int m = 32; m >= 1; m >>= 1) {
#pragma unroll
            for (int r = 0; r < TR; ++r) {
                float os = __shfl_xor(sb[r], m, 64);
                int   oi = __shfl_xor(ib[r], m, 64);
                if (os > sb[r] || (os == sb[r] && oi < ib[r])) {
                    sb[r] = os; ib[r] = oi;
                }
            }
        }
        if (cg == 0) {
#pragma unroll
            for (int r = 0; r < TR; ++r) {
                redS[cwgrp * BM + r0 + r] = sb[r];
                redI[cwgrp * BM + r0 + r] = ib[r];
            }
        }
        __syncthreads();
        // combine the two cw-groups per row (global first-occurrence ties)
        if (tid < BM) {
            float s0 = redS[tid], s1 = redS[BM + tid];
            int   i0 = redI[tid], i1 = redI[BM + tid];
            idx_s[g * BM + tid] =
                (s1 > s0 || (s1 == s0 && i1 < i0)) ? i1 : i0;
        }
        __syncthreads();

        // ---- residual -= chosen codeword (exact fp32); skip after last ----
        if (g < NG - 1) {
            const int row = tid >> 4;
            const int sub = tid & 15;
            const float4* crow =
                (const float4*)(C + (size_t)idx_s[g * BM + row] * DDIM);
            float4* rrow = (float4*)&resid[row * DDIM];
#pragma unroll
            for (int k = 0; k < 8; ++k) {
                int p = sub + k * 16;
                float4 rv = rrow[p], cv = crow[p];
                rv.x -= cv.x; rv.y -= cv.y; rv.z -= cv.z; rv.w -= cv.w;
                rrow[p] = rv;
            }
            __syncthreads();
        }
    }

    // ---- 3) st = z + (zq - z), zq in reference order (((0+q0)+q1)+q2)+q3 ----
    {
        const int row = tid >> 4;
        const int sub = tid & 15;
        const float4* zrow = (const float4*)(z + (row0 + row) * DDIM);
        float4* rrow = (float4*)&resid[row * DDIM];
        const float4* c0 = (const float4*)(cb + ((size_t)0 * NK + idx_s[0 * BM + row]) * DDIM);
        const float4* c1 = (const float4*)(cb + ((size_t)1 * NK + idx_s[1 * BM + row]) * DDIM);
        const float4* c2 = (const float4*)(cb + ((size_t)2 * NK + idx_s[2 * BM + row]) * DDIM);
        const float4* c3 = (const float4*)(cb + ((size_t)3 * NK + idx_s[3 * BM + row]) * DDIM);
#pragma unroll
        for (int k = 0; k < 8; ++k) {
            int p = sub + k * 16;
            float4 q0 = c0[p], q1 = c1[p], q2 = c2[p], q3 = c3[p];
            float4 q;
            q.x = ((q0.x + q1.x) + q2.x) + q3.x;
            q.y = ((q0.y + q1.y) + q2.y) + q3.y;
            q.z = ((q0.z + q1.z) + q2.z) + q3.z;
            q.w = ((q0.w + q1.w) + q2.w) + q3.w;
            float4 zv = zrow[p];
            float4 st;
            st.x = zv.x + (q.x - zv.x);
            st.y = zv.y + (q.y - zv.y);
            st.z = zv.z + (q.z - zv.z);
            st.w = zv.w + (q.w - zv.w);
            rrow[p] = st;
        }
    }
    __syncthreads();

    const int colg = tid & 31;
    const int rowg = tid >> 5;
    const int c0_  = colg * 4;
    const int hr0  = rowg * 2;

    // ---- 4) h1 = relu(st @ w1 + b1) ----
    {
        float acc[2][4] = {{0.f, 0.f, 0.f, 0.f}, {0.f, 0.f, 0.f, 0.f}};
        for (int d = 0; d < DDIM; d += 4) {
            float4 a0 = *(const float4*)&resid[hr0 * DDIM + d];
            float4 a1 = *(const float4*)&resid[(hr0 + 1) * DDIM + d];
            float a0f[4] = {a0.x, a0.y, a0.z, a0.w};
            float a1f[4] = {a1.x, a1.y, a1.z, a1.w};
#pragma unroll
            for (int dd = 0; dd < 4; ++dd) {
                float4 wv2 = *(const float4*)&w1[(size_t)(d + dd) * NH + c0_];
                acc[0][0] = fmaf(a0f[dd], wv2.x, acc[0][0]);
                acc[0][1] = fmaf(a0f[dd], wv2.y, acc[0][1]);
                acc[0][2] = fmaf(a0f[dd], wv2.z, acc[0][2]);
                acc[0][3] = fmaf(a0f[dd], wv2.w, acc[0][3]);
                acc[1][0] = fmaf(a1f[dd], wv2.x, acc[1][0]);
                acc[1][1] = fmaf(a1f[dd], wv2.y, acc[1][1]);
                acc[1][2] = fmaf(a1f[dd], wv2.z, acc[1][2]);
                acc[1][3] = fmaf(a1f[dd], wv2.w, acc[1][3]);
            }
        }
        float4 bv = *(const float4*)&b1[c0_];
        float bf[4] = {bv.x, bv.y, bv.z, bv.w};
#pragma unroll
        for (int r = 0; r < 2; ++r) {
            float4 o;
            o.x = fmaxf(acc[r][0] + bf[0], 0.f);
            o.y = fmaxf(acc[r][1] + bf[1], 0.f);
            o.z = fmaxf(acc[r][2] + bf[2], 0.f);
            o.w = fmaxf(acc[r][3] + bf[3], 0.f);
            *(float4*)&h1[(hr0 + r) * NH + c0_] = o;
        }
    }
    __syncthreads();

    // ---- 5) h2 = relu(h1 @ w2 + b2), stored into resid region ----
    float* h2 = resid;
    {
        float acc[2][4] = {{0.f, 0.f, 0.f, 0.f}, {0.f, 0.f, 0.f, 0.f}};
        for (int d = 0; d < NH; d += 4) {
            float4 a0 = *(const float4*)&h1[hr0 * NH + d];
            float4 a1 = *(const float4*)&h1[(hr0 + 1) * NH + d];
            float a0f[4] = {a0.x, a0.y, a0.z, a0.w};
            float a1f[4] = {a1.x, a1.y, a1.z, a1.w};
#pragma unroll
            for (int dd = 0; dd < 4; ++dd) {
                float4 wv2 = *(const float4*)&w2[(size_t)(d + dd) * NH + c0_];
                acc[0][0] = fmaf(a0f[dd], wv2.x, acc[0][0]);
                acc[0][1] = fmaf(a0f[dd], wv2.y, acc[0][1]);
                acc[0][2] = fmaf(a0f[dd], wv2.z, acc[0][2]);
                acc[0][3] = fmaf(a0f[dd], wv2.w, acc[0][3]);
                acc[1][0] = fmaf(a1f[dd], wv2.x, acc[1][0]);
                acc[1][1] = fmaf(a1f[dd], wv2.y, acc[1][1]);
                acc[1][2] = fmaf(a1f[dd], wv2.z, acc[1][2]);
                acc[1][3] = fmaf(a1f[dd], wv2.w, acc[1][3]);
            }
        }
        float4 bv = *(const float4*)&b2[c0_];
        float bf[4] = {bv.x, bv.y, bv.z, bv.w};
        __syncthreads();
#pragma unroll
        for (int r = 0; r < 2; ++r) {
            float4 o;
            o.x = fmaxf(acc[r][0] + bf[0], 0.f);
            o.y = fmaxf(acc[r][1] + bf[1], 0.f);
            o.z = fmaxf(acc[r][2] + bf[2], 0.f);
            o.w = fmaxf(acc[r][3] + bf[3], 0.f);
            *(float4*)&h2[(hr0 + r) * NH + c0_] = o;
        }
    }
    __syncthreads();

    // ---- 6) out = h2 @ w3 + b3 ----
    if (tid < BM * NA) {
        const int r = tid / NA;
        const int a = tid - r * NA;
        const float* h2r = &h2[r * NH];
        float s = b3[a];
        for (int h = 0; h < NH; ++h)
            s = fmaf(h2r[h], w3[(size_t)h * NA + a], s);
        out[(row0 + r) * NA + a] = s;
    }
}

extern "C" void kernel_launch(void* const* d_in, const int* in_sizes, int n_in,
                              void* d_out, int out_size, void* d_ws, size_t ws_size,
                              hipStream_t stream) {
    const float* z  = (const float*)d_in[0];
    const float* cb = (const float*)d_in[1];
    const float* w1 = (const float*)d_in[2];
    const float* b1 = (const float*)d_in[3];
    const float* w2 = (const float*)d_in[4];
    const float* b2 = (const float*)d_in[5];
    const float* w3 = (const float*)d_in[6];
    const float* b3 = (const float*)d_in[7];
    float* out = (float*)d_out;
    float* halfnorm = (float*)d_ws;   // NG*NK floats = 16 KB

    (void)hipFuncSetAttribute((const void*)rvq_mlp_fused,
                              hipFuncAttributeMaxDynamicSharedMemorySize,
                              LDS_BYTES);

    rvq_norms_np<<<dim3((NG * NK + 255) / 256), dim3(256), 0, stream>>>(cb, halfnorm);
    rvq_mlp_fused<<<dim3(B_ROWS / BM), dim3(NTHREADS), LDS_BYTES, stream>>>(
        z, cb, halfnorm, w1, b1, w2, b2, w3, b3, out);
}